// Round 2
// baseline (194.752 us; speedup 1.0000x reference)
//
#include <hip/hip_runtime.h>
#include <stdint.h>

// proj = einsum('bit,ih->tbh', x, W); scan: h=relu(p+0.8h(1-y)); y=thr(h+b,1).
// B=64, K=512, T=512, H=1024 fp32. Output: final y (64x1024).
//
// R7: pipeline fused_main. R6 post-mortem: prepass was already near its
// floor (~25-30us of the ~91us non-fused residual is harness dispatches);
// the controllable cost is fused_main's serial 2-barrier k-loop
// (stage -> drain -> consume -> drain, 1 block/CU, MfmaUtil 43%).
// This round: double-buffered 2-phase k-loop (T3/T4 minimal form):
//   stage(kt+1 -> buf^1); ds_read frags + 96 MFMA on buf; s_waitcnt(0);
//   barrier  -- ONE drain per iter, DMA latency hidden under MFMA.
// + T5 setprio(1) around the MFMA cluster (wave role diversity now exists).
// LDS: 2x64KB staging dbuf; epilogue P aliases buf1 (free after last
// k-step) as P[64][256] fp32 with XOR-bit4 swizzle keyed ((row>>2)&1)
// -> 2-way bank aliasing (free) on both write and read. Total 128KB.
// Next-tile first stage pre-issued under the epilogue (targets buf0).
// Math + MFMA order bit-identical to R5/R6; absmax must hold at 0.03125.

#define NB 64
#define NK 512
#define NT 512
#define NH 1024

#define TB 256     // t per block tile
#define HB 256     // h per block tile
#define KK 32      // k per step

typedef _Float16 h8_t __attribute__((ext_vector_type(8)));
typedef float    f4_t __attribute__((ext_vector_type(4)));

#define AS1 __attribute__((address_space(1)))
#define AS3 __attribute__((address_space(3)))

__device__ __forceinline__ void async_copy16(const _Float16* g, _Float16* l) {
    __builtin_amdgcn_global_load_lds((const AS1 uint32_t*)g, (AS3 uint32_t*)l, 16, 0, 0);
}

// full drain + barrier: single sync point per k-iteration
__device__ __forceinline__ void wait_all_barrier() {
    __builtin_amdgcn_s_waitcnt(0);   // vmcnt(0) expcnt(0) lgkmcnt(0)
    __syncthreads();
}

// ---- pre-pass (unchanged from R6): fp32 [rows][C] -> fp16 hi/lo in
// fragment order, coalesced float4 reads, dense h8 stores.
__global__ __launch_bounds__(256) void split_tc(
    const float* __restrict__ X, const float* __restrict__ Wm,
    _Float16* __restrict__ xhi, _Float16* __restrict__ xlo,
    _Float16* __restrict__ whi, _Float16* __restrict__ wlo)
{
    const int tid = threadIdx.x;
    const int cq  = tid & 15;     // col quad 0..15
    const int u   = tid >> 4;     // row octet 0..15

    const float* src;
    _Float16 *dhi, *dlo;
    int C, col0, row0, ktbase;

    if (blockIdx.z < 32) {
        const int idx = blockIdx.y * 16 + blockIdx.x;   // 0..63
        const int b   = blockIdx.z * 2 + (idx >> 5);    // 0..63
        const int i5  = idx & 31;
        const int bx  = i5 & 7;                          // col tile 0..7
        const int by  = i5 >> 3;                         // row tile 0..3
        C      = NT;                                     // 512
        src    = X + (size_t)b * NK * NT;
        dhi    = xhi;  dlo = xlo;
        col0   = bx * 64;
        row0   = by * 128;
        ktbase = b * 16 + by * 4;
    } else {
        const int bx = blockIdx.x;                       // 0..15
        const int by = blockIdx.y;                       // 0..3
        C      = NH;                                     // 1024
        src    = Wm;
        dhi    = whi;  dlo = wlo;
        col0   = bx * 64;
        row0   = by * 128;
        ktbase = by * 4;
    }

    const float* s = src + (size_t)(row0 + u * 8) * C + col0 + cq * 4;

    f4_t v[8];
    #pragma unroll
    for (int j = 0; j < 8; ++j)
        v[j] = *(const f4_t*)(s + (size_t)j * C);

    const int kt = ktbase + (u >> 2);
    const int ck = u & 3;

    #pragma unroll
    for (int i = 0; i < 4; ++i) {
        h8_t hi, lo;
        #pragma unroll
        for (int j = 0; j < 8; ++j) {
            float f = v[j][i] * 64.0f;       // 2^6 pre-scale
            _Float16 hh = (_Float16)f;
            hi[j] = hh;
            lo[j] = (_Float16)(f - (float)hh);
        }
        const int col = col0 + cq * 4 + i;
        const int ckp = ck ^ ((col >> 1) & 3);
        const size_t off = ((size_t)kt * C + col) * 32 + (size_t)ckp * 8;
        *(h8_t*)(dhi + off) = hi;
        *(h8_t*)(dlo + off) = lo;
    }
}

// ---------------- main fused kernel (R7: 2-phase dbuf pipeline) ----------------
__global__ __launch_bounds__(512, 2) void fused_main(
    const _Float16* __restrict__ xhi, const _Float16* __restrict__ xlo,
    const _Float16* __restrict__ whi, const _Float16* __restrict__ wlo,
    const float* __restrict__ bias, float* __restrict__ out)
{
    // [buf][arr][TB*KK] halfs; arr: 0=Ahi 1=Alo 2=Bhi 3=Blo. 131072 B total.
    __shared__ __align__(16) _Float16 SMEM[2][4][TB * KK];
    // Epilogue P aliases buf1 (64 KB): P[64][256] fp32, XOR-bit4 swizzled.
    float* Pf = (float*)&SMEM[1][0][0];

    const int tid  = threadIdx.x;
    const int lane = tid & 63;
    const int wid  = tid >> 6;     // 0..7
    const int l15  = lane & 15;
    const int lq   = lane >> 4;    // 0..3
    const int wm   = wid >> 1;     // t quarter 0..3
    const int wn   = wid & 1;      // h half 0..1

    const int b  = blockIdx.x;
    const int h0 = blockIdx.y * HB;

    // fragment LDS offsets (halfs); chunk swizzle matches pre-pass
    const int sw   = (l15 >> 1) & 3;
    const int aoff = ((wm * 64 + l15) * 4 + (lq ^ sw)) * 8;   // + mi*512
    const int boff = ((wn * 128 + l15) * 4 + (lq ^ sw)) * 8;  // + ni*512

    float hs = 0.0f, ys = 0.0f, bv = 0.0f;
    if (tid < HB) bv = bias[h0 + tid];

    const float INV_SCALE = 1.0f / 4096.0f;   // undo 2^6 x 2^6 operand scales

    // stage tile (tt, kt) into buffer `buf`: 4 arrays x 1024 16B-chunks.
    // LDS dest = wave-uniform base + lane*16 (global_load_lds constraint).
    auto stage = [&](int tt, int kt, int buf) {
        const _Float16* ga_hi = xhi + ((size_t)(b * 16 + kt) * NT + tt) * KK;
        const _Float16* ga_lo = xlo + ((size_t)(b * 16 + kt) * NT + tt) * KK;
        const _Float16* gb_hi = whi + ((size_t)kt * NH + h0) * KK;
        const _Float16* gb_lo = wlo + ((size_t)kt * NH + h0) * KK;
        _Float16* dAh = &SMEM[buf][0][0];
        _Float16* dAl = &SMEM[buf][1][0];
        _Float16* dBh = &SMEM[buf][2][0];
        _Float16* dBl = &SMEM[buf][3][0];
        #pragma unroll
        for (int c = 0; c < 2; ++c) {
            const int ch = tid + c * 512;
            async_copy16(ga_hi + ch * 8, dAh + ch * 8);
            async_copy16(ga_lo + ch * 8, dAl + ch * 8);
            async_copy16(gb_hi + ch * 8, dBh + ch * 8);
            async_copy16(gb_lo + ch * 8, dBl + ch * 8);
        }
    };

    f4_t acc[4][8];

    stage(0, 0, 0);   // prologue for first t-tile

    for (int tt0 = 0; tt0 < NT; tt0 += TB) {
        #pragma unroll
        for (int mi = 0; mi < 4; ++mi)
            #pragma unroll
            for (int ni = 0; ni < 8; ++ni) {
                f4_t z = {0.f, 0.f, 0.f, 0.f};
                acc[mi][ni] = z;
            }

        wait_all_barrier();   // prologue loads (issued pre-loop/pre-epilogue) landed

        for (int kt = 0; kt < NK / KK; ++kt) {
            const int cur = kt & 1;
            // issue next tile's DMA into the other buffer; it flies under MFMA
            if (kt + 1 < NK / KK) stage(tt0, kt + 1, cur ^ 1);

            const _Float16* Ah = &SMEM[cur][0][0];
            const _Float16* Al = &SMEM[cur][1][0];
            const _Float16* Bh = &SMEM[cur][2][0];
            const _Float16* Bl = &SMEM[cur][3][0];

            h8_t bh[8], bl[8];
            #pragma unroll
            for (int ni = 0; ni < 8; ++ni) {
                bh[ni] = *(const h8_t*)(Bh + boff + ni * 512);
                bl[ni] = *(const h8_t*)(Bl + boff + ni * 512);
            }
            __builtin_amdgcn_s_setprio(1);
            #pragma unroll
            for (int mi = 0; mi < 4; ++mi) {
                h8_t ah = *(const h8_t*)(Ah + aoff + mi * 512);
                h8_t al = *(const h8_t*)(Al + aoff + mi * 512);
                #pragma unroll
                for (int ni = 0; ni < 8; ++ni) {
                    acc[mi][ni] = __builtin_amdgcn_mfma_f32_16x16x32_f16(ah, bh[ni], acc[mi][ni], 0, 0, 0);
                    acc[mi][ni] = __builtin_amdgcn_mfma_f32_16x16x32_f16(ah, bl[ni], acc[mi][ni], 0, 0, 0);
                    acc[mi][ni] = __builtin_amdgcn_mfma_f32_16x16x32_f16(al, bh[ni], acc[mi][ni], 0, 0, 0);
                }
            }
            __builtin_amdgcn_s_setprio(0);

            wait_all_barrier();   // single drain: next-buf DMA done, all frag reads retired
        }

        // pre-issue next t-tile's first stage into buf0 (overlaps epilogue; P is buf1)
        if (tt0 + TB < NT) stage(tt0 + TB, 0, 0);

        // epilogue: 4 t-subtiles x 64 rows; P[64][256] fp32 aliased on buf1.
        // Swizzle: col' = col ^ (((row>>2)&1)<<4); writer key (lq&1) == reader
        // key ((m>>2)&1) since row = mi*16 + lq*4 + r. 2-way banks both sides.
        #pragma unroll 1
        for (int sub = 0; sub < 4; ++sub) {
            if (wm == sub) {
                #pragma unroll
                for (int mi = 0; mi < 4; ++mi)
                    #pragma unroll
                    for (int ni = 0; ni < 8; ++ni)
                        #pragma unroll
                        for (int r = 0; r < 4; ++r) {
                            const int row = mi * 16 + lq * 4 + r;
                            const int col = (wn * 128 + ni * 16 + l15) ^ ((lq & 1) << 4);
                            Pf[row * 256 + col] = acc[mi][ni][r] * INV_SCALE;
                        }
            }
            __syncthreads();
            if (tid < HB) {
                const int cc = tid;   // h within block tile, 0..255
                #pragma unroll 8
                for (int m = 0; m < 64; ++m) {
                    float p = Pf[m * 256 + (cc ^ (((m >> 2) & 1) << 4))];
                    float pre = p + 0.8f * hs * (1.0f - ys);
                    hs = pre > 0.0f ? pre : 0.0f;
                    float z = hs + bv;
                    ys = (z > 1.0f) ? z : 0.0f;
                }
            }
            __syncthreads();   // scan done before next sub overwrites P
        }
    }

    if (tid < HB)
        out[(size_t)b * NH + h0 + tid] = ys;
}

extern "C" void kernel_launch(void* const* d_in, const int* in_sizes, int n_in,
                              void* d_out, int out_size, void* d_ws, size_t ws_size,
                              hipStream_t stream) {
    const float* x    = (const float*)d_in[0];  // [64][512][512]
    const float* W    = (const float*)d_in[1];  // [512][1024]
    const float* bias = (const float*)d_in[2];  // [1024]
    float* out = (float*)d_out;

    _Float16* xhi = (_Float16*)d_ws;
    _Float16* xlo = xhi + (size_t)NB * NK * NT;
    _Float16* whi = xlo + (size_t)NB * NK * NT;
    _Float16* wlo = whi + (size_t)NK * NH;

    split_tc<<<dim3(16, 4, 33), 256, 0, stream>>>(x, W, xhi, xlo, whi, wlo);
    fused_main<<<dim3(NB, NH / HB), 512, 0, stream>>>(xhi, xlo, whi, wlo, bias, out);
}